// Round 12
// baseline (47.283 us; speedup 1.0000x reference)
//
#include <hip/hip_runtime.h>
#include <cstdint>
#include <cstddef>

#define TINV 5.0f
#define C5L2E 7.2134752044448170f   // 5 * log2(e)
#define NROWS 4096
#define DDIM 256
#define MM 8192

typedef __bf16 bf16x8 __attribute__((ext_vector_type(8)));
typedef int i32x4 __attribute__((ext_vector_type(4)));
typedef float f32x4 __attribute__((ext_vector_type(4)));

typedef const void __attribute__((address_space(1)))* gas_ptr;
typedef void __attribute__((address_space(3)))* las_ptr;

// ------- normalize rows of [Z1;Z2] -> unit L2, store bf16; zero rowsumAcc -------
__global__ __launch_bounds__(256, 2)
void nrm_kernel(const float* __restrict__ Z1, const float* __restrict__ Z2,
                unsigned short* __restrict__ Zb, float* __restrict__ rowsumAcc) {
    if (blockIdx.x < 32) rowsumAcc[blockIdx.x * 256 + threadIdx.x] = 0.f;
    const int w = threadIdx.x >> 6, lane = threadIdx.x & 63;
    const int row = blockIdx.x * 4 + w;
    const float* src = row < NROWS ? Z1 + (size_t)row * DDIM
                                   : Z2 + (size_t)(row - NROWS) * DDIM;
    float4 v = reinterpret_cast<const float4*>(src)[lane];
    float ss = v.x*v.x + v.y*v.y + v.z*v.z + v.w*v.w;
    #pragma unroll
    for (int m = 1; m < 64; m <<= 1) ss += __shfl_xor(ss, m, 64);
    float inv = 1.0f / fmaxf(sqrtf(ss), 1e-12f);
    float o[4] = { v.x*inv, v.y*inv, v.z*inv, v.w*inv };
    unsigned short us[4];
    #pragma unroll
    for (int e = 0; e < 4; ++e) {           // RNE f32->bf16 (finite inputs)
        unsigned int b = __builtin_bit_cast(unsigned int, o[e]);
        b += 0x7FFFu + ((b >> 16) & 1u);
        us[e] = (unsigned short)(b >> 16);
    }
    reinterpret_cast<ushort4*>(Zb + (size_t)row * DDIM)[lane] =
        *reinterpret_cast<ushort4*>(us);
}

// ---- stage 64 rows x 512B (32KB) into LDS with 256 threads; source pre-swizzled ----
// read side uses phys_inrow = inrow ^ ((row&15)<<4)
__device__ __forceinline__ void stage32(const unsigned short* Zb, char* ldsdst,
                                        int rowStart, int tid) {
    const char* base = reinterpret_cast<const char*>(Zb) + (size_t)rowStart * 512;
    #pragma unroll
    for (int it = 0; it < 8; ++it) {
        int L = it * 4096 + tid * 16;     // linear LDS byte offset, lane-contiguous
        int row = L >> 9;                 // 0..63
        int soff = row * 512 + ((L & 511) ^ ((row & 15) << 4));
        __builtin_amdgcn_global_load_lds((gas_ptr)(base + soff), (las_ptr)(ldsdst + L),
                                         16, 0, 0);
    }
}

// -------- symmetric fused sim + exp-rowsum/colsum + pos extraction --------
// R11 schedule (64 bands x 128 rows, 8 splits, 2x2 wave grid, A in AGPR, colsum
// symmetry into colPartLds). R12 change: phase body reordered for pipe overlap —
// b0 loads -> MFMA0 -> b1 loads (hoist into MFMA0 shadow) -> MFMA1 -> epilogues
// (epilogue0 VALU co-issues with MFMA1 on the separate matrix pipe).
__global__ __launch_bounds__(256, 2)
void sim_lse_kernel(const unsigned short* __restrict__ Zb,
                    float* __restrict__ rowsumAcc,  // [MM], atomic accum
                    float* __restrict__ posArr) {   // [MM]
    __shared__ char lds[65536];                     // 2 x 32KB B buffers
    __shared__ float colPartLds[4][8][32];          // 4 KB colsum partials
    const int tid = threadIdx.x;
    const int lane = tid & 63;
    const int w = tid >> 6;
    const int wr = w >> 1, wc = w & 1;              // wave row-group / col-half
    const int r15 = lane & 15, hi = lane >> 4;
    const int r = blockIdx.x >> 3;                  // band 0..63
    const int s = blockIdx.x & 7;                   // split 0..7
    const int e0 = r & 7, e1 = e0 ^ 4;              // which splits take d=32 halves
    const int nt = 8 + ((s == e0) || (s == e1));
    const int extraHalf = (s == e1) ? 1 : 0;
    const int R0 = r * 128;

    // diag phases (s==0, t<2) never write colsums: zero own-wave slots
    if (s == 0 && lane < 32) {
        colPartLds[w][0][lane] = 0.f;
        colPartLds[w][1][lane] = 0.f;
    }

    // thread-constant swizzled k-chunk offsets (row&15 == r15 for every frag read)
    int koff[8];
    #pragma unroll
    for (int kk = 0; kk < 8; ++kk)
        koff[kk] = ((hi << 4) | (kk << 6)) ^ (r15 << 4);

    // ---- stage A band (128 rows) across both buffers, pull frags to registers ----
    stage32(Zb, lds, R0, tid);
    stage32(Zb, lds + 32768, R0 + 64, tid);
    __syncthreads();
    i32x4 qf[4][8];                                 // 64 rows x K=256 -> AGPRs
    {
        const char* ab = lds + (wr << 15);          // wr: which 64-row buffer
        #pragma unroll
        for (int mf = 0; mf < 4; ++mf)
            #pragma unroll
            for (int kk = 0; kk < 8; ++kk)
                qf[mf][kk] = *reinterpret_cast<const i32x4*>(
                    ab + (mf * 16 + r15) * 512 + koff[kk]);
    }
    __syncthreads();

    int baddr[8];                                   // wave's 32-col half of B tile
    #pragma unroll
    for (int kk = 0; kk < 8; ++kk)
        baddr[kk] = (wc * 32 + r15) * 512 + koff[kk];

    float rowsum[4][4] = {{0,0,0,0},{0,0,0,0},{0,0,0,0},{0,0,0,0}};
    const int iBase = R0 + wr * 64 + (hi << 2);     // C/D: row=(lane>>4)*4+rr

    // column start (Zb row units) of subtile step t
    auto colOf = [&](int t) -> int {
        int d = (t < 8) ? (s + ((t >> 1) << 3)) : 32;
        int half = (t < 8) ? (t & 1) : extraHalf;
        return ((r + d) & 63) * 128 + half * 64;
    };

    // per-nf epilogue (mode 0: rowsum+colsum; 1: diag skip; 2: rowsum+pos)
    auto epi = [&](const f32x4 (&a)[4], int j, int t, int nf, int mode) {
        if (mode == 0) {
            float s8 = 0.f;
            #pragma unroll
            for (int mf = 0; mf < 4; ++mf)
                #pragma unroll
                for (int rr = 0; rr < 4; ++rr) {
                    float e = __builtin_amdgcn_exp2f(fmaf(a[mf][rr], C5L2E, -C5L2E));
                    rowsum[mf][rr] += e;
                    s8 += e;
                }
            s8 += __shfl_xor(s8, 16, 64);           // sum the 4 hi-groups (64 rows)
            s8 += __shfl_xor(s8, 32, 64);
            if (hi == 0) colPartLds[w][t][nf * 16 + r15] = s8;  // unique slot
        } else if (mode == 1) {
            #pragma unroll
            for (int mf = 0; mf < 4; ++mf)
                #pragma unroll
                for (int rr = 0; rr < 4; ++rr) {
                    const int i = iBase + mf * 16 + rr;
                    if (j != i)
                        rowsum[mf][rr] += __builtin_amdgcn_exp2f(fmaf(a[mf][rr], C5L2E, -C5L2E));
                }
        } else {
            #pragma unroll
            for (int mf = 0; mf < 4; ++mf)
                #pragma unroll
                for (int rr = 0; rr < 4; ++rr) {
                    const int i = iBase + mf * 16 + rr;
                    rowsum[mf][rr] += __builtin_amdgcn_exp2f(fmaf(a[mf][rr], C5L2E, -C5L2E));
                    if (j == (i ^ 4096)) posArr[i] = a[mf][rr] * TINV;  // unique
                }
        }
    };

    stage32(Zb, lds, colOf(0), tid);                // subtile 0 -> buf0

    for (int t = 0; t < nt; ++t) {
        const int C0 = colOf(t);
        const int cur = (t & 1) << 15;
        if (t < nt - 1) {
            stage32(Zb, lds + (cur ^ 32768), colOf(t + 1), tid);
            asm volatile("s_waitcnt vmcnt(8)" ::: "memory");   // cur's 8 loads done
        } else {
            asm volatile("s_waitcnt vmcnt(0)" ::: "memory");
        }
        __builtin_amdgcn_s_barrier();
        __builtin_amdgcn_sched_barrier(0);

        const int mode = (t == 8) ? 2 : ((s == 0 && t < 2) ? 1 : 0);

        f32x4 acc0[4] = {{0,0,0,0},{0,0,0,0},{0,0,0,0},{0,0,0,0}};
        f32x4 acc1[4] = {{0,0,0,0},{0,0,0,0},{0,0,0,0},{0,0,0,0}};
        {
            i32x4 b0[8];
            #pragma unroll
            for (int kk = 0; kk < 8; ++kk)
                b0[kk] = *reinterpret_cast<const i32x4*>(lds + cur + baddr[kk]);
            #pragma unroll
            for (int kk = 0; kk < 8; ++kk)
                #pragma unroll
                for (int mf = 0; mf < 4; ++mf)
                    asm("v_mfma_f32_16x16x32_bf16 %0, %1, %2, %0"
                        : "+v"(acc0[mf]) : "a"(qf[mf][kk]), "v"(b0[kk]));
        }
        {
            i32x4 b1[8];
            #pragma unroll
            for (int kk = 0; kk < 8; ++kk)
                b1[kk] = *reinterpret_cast<const i32x4*>(lds + cur + 8192 + baddr[kk]);
            #pragma unroll
            for (int kk = 0; kk < 8; ++kk)
                #pragma unroll
                for (int mf = 0; mf < 4; ++mf)
                    asm("v_mfma_f32_16x16x32_bf16 %0, %1, %2, %0"
                        : "+v"(acc1[mf]) : "a"(qf[mf][kk]), "v"(b1[kk]));
        }
        // epilogue0 (VALU) co-issues with tail of MFMA1 (matrix pipe)
        epi(acc0, C0 + wc * 32 + r15, t, 0, mode);
        epi(acc1, C0 + wc * 32 + 16 + r15, t, 1, mode);

        asm volatile("" ::: "memory");
        __builtin_amdgcn_sched_barrier(0);
        __builtin_amdgcn_s_barrier();               // done reading cur before overwrite
    }

    // ---- one-time colsum flush: 8 tiles x 64 cols = 512 targets = 2/thread ----
    __syncthreads();                                // colPartLds writes visible
    #pragma unroll
    for (int z = 0; z < 2; ++z) {
        const int idx = z * 256 + tid;              // t*64 + c
        const int tt = idx >> 6, c = idx & 63;
        const int ww = c >> 5;                      // which wc owns column c
        float v = colPartLds[ww][tt][c & 31] + colPartLds[2 + ww][tt][c & 31];
        if (v != 0.f) atomicAdd(&rowsumAcc[colOf(tt) + c], v);
    }

    // reduce rowsums across the 16 lanes sharing each row, flush atomically
    #pragma unroll
    for (int mf = 0; mf < 4; ++mf)
        #pragma unroll
        for (int rr = 0; rr < 4; ++rr) {
            float v = rowsum[mf][rr];
            v += __shfl_xor(v, 1, 64);
            v += __shfl_xor(v, 2, 64);
            v += __shfl_xor(v, 4, 64);
            v += __shfl_xor(v, 8, 64);
            if (r15 == 0) atomicAdd(&rowsumAcc[iBase + mf * 16 + rr], v);
        }
}

// ------- finish (single kernel): lse = log(sum)+5; out = mean(lse - pos) -------
__global__ __launch_bounds__(1024)
void fin_kernel(const float* __restrict__ rowsumAcc, const float* __restrict__ posArr,
                float* __restrict__ out) {
    const int tid = threadIdx.x;
    double v = 0.0;
    #pragma unroll
    for (int z = 0; z < 8; ++z) {
        const int i = z * 1024 + tid;
        v += (double)(logf(rowsumAcc[i]) + 5.0f - posArr[i]);
    }
    #pragma unroll
    for (int m = 1; m < 64; m <<= 1) v += __shfl_xor(v, m, 64);
    __shared__ double red[16];
    if ((tid & 63) == 0) red[tid >> 6] = v;
    __syncthreads();
    if (tid == 0) {
        double s = 0.0;
        #pragma unroll
        for (int k = 0; k < 16; ++k) s += red[k];
        out[0] = (float)(s / (double)MM);
    }
}

extern "C" void kernel_launch(void* const* d_in, const int* in_sizes, int n_in,
                              void* d_out, int out_size, void* d_ws, size_t ws_size,
                              hipStream_t stream) {
    const float* Z1 = (const float*)d_in[0];
    const float* Z2 = (const float*)d_in[1];
    float* out = (float*)d_out;
    char* ws = (char*)d_ws;
    unsigned short* Zb = (unsigned short*)ws;                         // 4 MB bf16 [8192][256]
    float* posArr = (float*)(ws + 4194304);                           // 32 KB
    float* rowsumAcc = (float*)(ws + 4194304 + 32768);                // 32 KB

    nrm_kernel<<<MM / 4, 256, 0, stream>>>(Z1, Z2, Zb, rowsumAcc);
    sim_lse_kernel<<<64 * 8, 256, 0, stream>>>(Zb, rowsumAcc, posArr);
    fin_kernel<<<1, 1024, 0, stream>>>(rowsumAcc, posArr, out);
}

// Round 13
// 42.462 us; speedup vs baseline: 1.1135x; 1.1135x over previous
//
#include <hip/hip_runtime.h>
#include <cstdint>
#include <cstddef>

#define TINV 5.0f
#define C5L2E 7.2134752044448170f   // 5 * log2(e)
#define NROWS 4096
#define DDIM 256
#define MM 8192

typedef __bf16 bf16x8 __attribute__((ext_vector_type(8)));
typedef int i32x4 __attribute__((ext_vector_type(4)));
typedef float f32x4 __attribute__((ext_vector_type(4)));

typedef const void __attribute__((address_space(1)))* gas_ptr;
typedef void __attribute__((address_space(3)))* las_ptr;

// ------- normalize rows of [Z1;Z2] -> unit L2, store bf16; zero rowsumAcc -------
__global__ __launch_bounds__(256, 2)
void nrm_kernel(const float* __restrict__ Z1, const float* __restrict__ Z2,
                unsigned short* __restrict__ Zb, float* __restrict__ rowsumAcc) {
    if (blockIdx.x < 32) rowsumAcc[blockIdx.x * 256 + threadIdx.x] = 0.f;
    const int w = threadIdx.x >> 6, lane = threadIdx.x & 63;
    const int row = blockIdx.x * 4 + w;
    const float* src = row < NROWS ? Z1 + (size_t)row * DDIM
                                   : Z2 + (size_t)(row - NROWS) * DDIM;
    float4 v = reinterpret_cast<const float4*>(src)[lane];
    float ss = v.x*v.x + v.y*v.y + v.z*v.z + v.w*v.w;
    #pragma unroll
    for (int m = 1; m < 64; m <<= 1) ss += __shfl_xor(ss, m, 64);
    float inv = 1.0f / fmaxf(sqrtf(ss), 1e-12f);
    float o[4] = { v.x*inv, v.y*inv, v.z*inv, v.w*inv };
    unsigned short us[4];
    #pragma unroll
    for (int e = 0; e < 4; ++e) {           // RNE f32->bf16 (finite inputs)
        unsigned int b = __builtin_bit_cast(unsigned int, o[e]);
        b += 0x7FFFu + ((b >> 16) & 1u);
        us[e] = (unsigned short)(b >> 16);
    }
    reinterpret_cast<ushort4*>(Zb + (size_t)row * DDIM)[lane] =
        *reinterpret_cast<ushort4*>(us);
}

// ---- stage 64 rows x 512B (32KB) into LDS with 256 threads; source pre-swizzled ----
// read side uses phys_inrow = inrow ^ ((row&15)<<4)
__device__ __forceinline__ void stage32(const unsigned short* Zb, char* ldsdst,
                                        int rowStart, int tid) {
    const char* base = reinterpret_cast<const char*>(Zb) + (size_t)rowStart * 512;
    #pragma unroll
    for (int it = 0; it < 8; ++it) {
        int L = it * 4096 + tid * 16;     // linear LDS byte offset, lane-contiguous
        int row = L >> 9;                 // 0..63
        int soff = row * 512 + ((L & 511) ^ ((row & 15) << 4));
        __builtin_amdgcn_global_load_lds((gas_ptr)(base + soff), (las_ptr)(ldsdst + L),
                                         16, 0, 0);
    }
}

// -------- symmetric fused sim + exp-rowsum/colsum + pos extraction --------
// R11 schedule (64 bands x 128 rows, 8 splits, 2x2 wave grid, A in AGPR, colsum
// symmetry into colPartLds, no in-loop atomics). R13 change: SINGLE barrier per
// phase — __syncthreads (implicit vmcnt drain of own stage-t loads) THEN stage(t+1)
// into the buffer freed by phase t-1, then compute. Halves barrier count.
__global__ __launch_bounds__(256, 2)
void sim_lse_kernel(const unsigned short* __restrict__ Zb,
                    float* __restrict__ rowsumAcc,  // [MM], atomic accum
                    float* __restrict__ posArr) {   // [MM]
    __shared__ char lds[65536];                     // 2 x 32KB B buffers
    __shared__ float colPartLds[4][8][32];          // 4 KB colsum partials
    const int tid = threadIdx.x;
    const int lane = tid & 63;
    const int w = tid >> 6;
    const int wr = w >> 1, wc = w & 1;              // wave row-group / col-half
    const int r15 = lane & 15, hi = lane >> 4;
    const int r = blockIdx.x >> 3;                  // band 0..63
    const int s = blockIdx.x & 7;                   // split 0..7
    const int e0 = r & 7, e1 = e0 ^ 4;              // which splits take d=32 halves
    const int nt = 8 + ((s == e0) || (s == e1));
    const int extraHalf = (s == e1) ? 1 : 0;
    const int R0 = r * 128;

    // diag phases (s==0, t<2) never write colsums: zero own-wave slots
    if (s == 0 && lane < 32) {
        colPartLds[w][0][lane] = 0.f;
        colPartLds[w][1][lane] = 0.f;
    }

    // thread-constant swizzled k-chunk offsets (row&15 == r15 for every frag read)
    int koff[8];
    #pragma unroll
    for (int kk = 0; kk < 8; ++kk)
        koff[kk] = ((hi << 4) | (kk << 6)) ^ (r15 << 4);

    // ---- stage A band (128 rows) across both buffers, pull frags to registers ----
    stage32(Zb, lds, R0, tid);
    stage32(Zb, lds + 32768, R0 + 64, tid);
    __syncthreads();
    i32x4 qf[4][8];                                 // 64 rows x K=256 -> AGPRs
    {
        const char* ab = lds + (wr << 15);          // wr: which 64-row buffer
        #pragma unroll
        for (int mf = 0; mf < 4; ++mf)
            #pragma unroll
            for (int kk = 0; kk < 8; ++kk)
                qf[mf][kk] = *reinterpret_cast<const i32x4*>(
                    ab + (mf * 16 + r15) * 512 + koff[kk]);
    }
    __syncthreads();

    int baddr[8];                                   // wave's 32-col half of B tile
    #pragma unroll
    for (int kk = 0; kk < 8; ++kk)
        baddr[kk] = (wc * 32 + r15) * 512 + koff[kk];

    float rowsum[4][4] = {{0,0,0,0},{0,0,0,0},{0,0,0,0},{0,0,0,0}};
    const int iBase = R0 + wr * 64 + (hi << 2);     // C/D: row=(lane>>4)*4+rr

    // column start (Zb row units) of subtile step t
    auto colOf = [&](int t) -> int {
        int d = (t < 8) ? (s + ((t >> 1) << 3)) : 32;
        int half = (t < 8) ? (t & 1) : extraHalf;
        return ((r + d) & 63) * 128 + half * 64;
    };

    stage32(Zb, lds, colOf(0), tid);                // subtile 0 -> buf0

    for (int t = 0; t < nt; ++t) {
        const int C0 = colOf(t);
        const int cur = (t & 1) << 15;

        // ONE barrier per phase: implicit vmcnt(0) drains this thread's stage-t
        // loads (issued a full phase ago); barrier makes completion collective
        // AND guarantees all waves finished computing t-1, freeing its buffer.
        __syncthreads();
        if (t < nt - 1)
            stage32(Zb, lds + (cur ^ 32768), colOf(t + 1), tid);

        const int mode = (t == 8) ? 2 : ((s == 0 && t < 2) ? 1 : 0); // 0 norm,1 diag,2 pos
        #pragma unroll
        for (int nf = 0; nf < 2; ++nf) {
            f32x4 acc[4] = {{0,0,0,0},{0,0,0,0},{0,0,0,0},{0,0,0,0}};
            #pragma unroll
            for (int kk = 0; kk < 8; ++kk) {
                i32x4 b = *reinterpret_cast<const i32x4*>(lds + cur + nf * 8192 + baddr[kk]);
                #pragma unroll
                for (int mf = 0; mf < 4; ++mf)
                    asm("v_mfma_f32_16x16x32_bf16 %0, %1, %2, %0"
                        : "+v"(acc[mf]) : "a"(qf[mf][kk]), "v"(b));
            }
            const int j = C0 + wc * 32 + nf * 16 + r15;   // C/D: col=lane&15
            if (mode == 0) {
                float s8 = 0.f;
                #pragma unroll
                for (int mf = 0; mf < 4; ++mf)
                    #pragma unroll
                    for (int rr = 0; rr < 4; ++rr) {
                        float e = __builtin_amdgcn_exp2f(fmaf(acc[mf][rr], C5L2E, -C5L2E));
                        rowsum[mf][rr] += e;
                        s8 += e;
                    }
                s8 += __shfl_xor(s8, 16, 64);       // sum the 4 hi-groups (64 rows)
                s8 += __shfl_xor(s8, 32, 64);
                if (hi == 0) colPartLds[w][t][nf * 16 + r15] = s8;  // unique slot
            } else if (mode == 1) {
                #pragma unroll
                for (int mf = 0; mf < 4; ++mf)
                    #pragma unroll
                    for (int rr = 0; rr < 4; ++rr) {
                        const int i = iBase + mf * 16 + rr;
                        if (j != i)
                            rowsum[mf][rr] += __builtin_amdgcn_exp2f(fmaf(acc[mf][rr], C5L2E, -C5L2E));
                    }
            } else {
                #pragma unroll
                for (int mf = 0; mf < 4; ++mf)
                    #pragma unroll
                    for (int rr = 0; rr < 4; ++rr) {
                        const int i = iBase + mf * 16 + rr;
                        rowsum[mf][rr] += __builtin_amdgcn_exp2f(fmaf(acc[mf][rr], C5L2E, -C5L2E));
                        if (j == (i ^ 4096)) posArr[i] = acc[mf][rr] * TINV;  // unique
                    }
            }
        }
    }

    // ---- one-time colsum flush: 8 tiles x 64 cols = 512 targets = 2/thread ----
    __syncthreads();                                // colPartLds writes visible
    #pragma unroll
    for (int z = 0; z < 2; ++z) {
        const int idx = z * 256 + tid;              // t*64 + c
        const int tt = idx >> 6, c = idx & 63;
        const int ww = c >> 5;                      // which wc owns column c
        float v = colPartLds[ww][tt][c & 31] + colPartLds[2 + ww][tt][c & 31];
        if (v != 0.f) atomicAdd(&rowsumAcc[colOf(tt) + c], v);
    }

    // reduce rowsums across the 16 lanes sharing each row, flush atomically
    #pragma unroll
    for (int mf = 0; mf < 4; ++mf)
        #pragma unroll
        for (int rr = 0; rr < 4; ++rr) {
            float v = rowsum[mf][rr];
            v += __shfl_xor(v, 1, 64);
            v += __shfl_xor(v, 2, 64);
            v += __shfl_xor(v, 4, 64);
            v += __shfl_xor(v, 8, 64);
            if (r15 == 0) atomicAdd(&rowsumAcc[iBase + mf * 16 + rr], v);
        }
}

// ---------------- finish: lse = log(sum)+5; mean(lse - pos) ----------------
__global__ __launch_bounds__(128)
void fin1_kernel(const float* __restrict__ rowsumAcc, const float* __restrict__ posArr,
                 float* __restrict__ blockSums) {    // [64]
    const int tid = threadIdx.x;
    const int i = blockIdx.x * 128 + tid;
    double v = (double)(logf(rowsumAcc[i]) + 5.0f - posArr[i]);
    #pragma unroll
    for (int m = 1; m < 64; m <<= 1) v += __shfl_xor(v, m, 64);
    __shared__ double red[2];
    if ((tid & 63) == 0) red[tid >> 6] = v;
    __syncthreads();
    if (tid == 0) blockSums[blockIdx.x] = (float)(red[0] + red[1]);
}

__global__ __launch_bounds__(64)
void fin2_kernel(const float* __restrict__ blockSums, float* __restrict__ out) {
    double v = (double)blockSums[threadIdx.x];
    #pragma unroll
    for (int m = 1; m < 64; m <<= 1) v += __shfl_xor(v, m, 64);
    if (threadIdx.x == 0) out[0] = (float)(v / (double)MM);
}

extern "C" void kernel_launch(void* const* d_in, const int* in_sizes, int n_in,
                              void* d_out, int out_size, void* d_ws, size_t ws_size,
                              hipStream_t stream) {
    const float* Z1 = (const float*)d_in[0];
    const float* Z2 = (const float*)d_in[1];
    float* out = (float*)d_out;
    char* ws = (char*)d_ws;
    unsigned short* Zb = (unsigned short*)ws;                         // 4 MB bf16 [8192][256]
    float* posArr = (float*)(ws + 4194304);                           // 32 KB
    float* rowsumAcc = (float*)(ws + 4194304 + 32768);                // 32 KB
    float* blockSums = (float*)(ws + 4194304 + 65536);                // 256 B

    nrm_kernel<<<MM / 4, 256, 0, stream>>>(Z1, Z2, Zb, rowsumAcc);
    sim_lse_kernel<<<64 * 8, 256, 0, stream>>>(Zb, rowsumAcc, posArr);
    fin1_kernel<<<64, 128, 0, stream>>>(rowsumAcc, posArr, blockSums);
    fin2_kernel<<<1, 64, 0, stream>>>(blockSums, out);
}

// Round 14
// 39.659 us; speedup vs baseline: 1.1922x; 1.0707x over previous
//
#include <hip/hip_runtime.h>
#include <cstdint>
#include <cstddef>

#define TINV 5.0f
#define C5L2E 7.2134752044448170f   // 5 * log2(e)
#define NROWS 4096
#define DDIM 256
#define MM 8192

typedef __bf16 bf16x8 __attribute__((ext_vector_type(8)));
typedef int i32x4 __attribute__((ext_vector_type(4)));
typedef float f32x4 __attribute__((ext_vector_type(4)));

typedef const void __attribute__((address_space(1)))* gas_ptr;
typedef void __attribute__((address_space(3)))* las_ptr;

// ------- normalize rows of [Z1;Z2] -> unit L2, store bf16; zero rowsumAcc -------
__global__ __launch_bounds__(256, 2)
void nrm_kernel(const float* __restrict__ Z1, const float* __restrict__ Z2,
                unsigned short* __restrict__ Zb, float* __restrict__ rowsumAcc) {
    if (blockIdx.x < 32) rowsumAcc[blockIdx.x * 256 + threadIdx.x] = 0.f;
    const int w = threadIdx.x >> 6, lane = threadIdx.x & 63;
    const int row = blockIdx.x * 4 + w;
    const float* src = row < NROWS ? Z1 + (size_t)row * DDIM
                                   : Z2 + (size_t)(row - NROWS) * DDIM;
    float4 v = reinterpret_cast<const float4*>(src)[lane];
    float ss = v.x*v.x + v.y*v.y + v.z*v.z + v.w*v.w;
    #pragma unroll
    for (int m = 1; m < 64; m <<= 1) ss += __shfl_xor(ss, m, 64);
    float inv = 1.0f / fmaxf(sqrtf(ss), 1e-12f);
    float o[4] = { v.x*inv, v.y*inv, v.z*inv, v.w*inv };
    unsigned short us[4];
    #pragma unroll
    for (int e = 0; e < 4; ++e) {           // RNE f32->bf16 (finite inputs)
        unsigned int b = __builtin_bit_cast(unsigned int, o[e]);
        b += 0x7FFFu + ((b >> 16) & 1u);
        us[e] = (unsigned short)(b >> 16);
    }
    reinterpret_cast<ushort4*>(Zb + (size_t)row * DDIM)[lane] =
        *reinterpret_cast<ushort4*>(us);
}

// ---- stage 64 rows x 512B (32KB) into LDS with 256 threads; source pre-swizzled ----
// read side uses phys_inrow = inrow ^ ((row&15)<<4)
__device__ __forceinline__ void stage32(const unsigned short* Zb, char* ldsdst,
                                        int rowStart, int tid) {
    const char* base = reinterpret_cast<const char*>(Zb) + (size_t)rowStart * 512;
    #pragma unroll
    for (int it = 0; it < 8; ++it) {
        int L = it * 4096 + tid * 16;     // linear LDS byte offset, lane-contiguous
        int row = L >> 9;                 // 0..63
        int soff = row * 512 + ((L & 511) ^ ((row & 15) << 4));
        __builtin_amdgcn_global_load_lds((gas_ptr)(base + soff), (las_ptr)(ldsdst + L),
                                         16, 0, 0);
    }
}

// -------- symmetric fused sim + exp-rowsum/colsum + pos extraction --------
// R13 schedule (64 bands x 128 rows, 8 splits, 2x2 wave grid, A in AGPR, colsum
// symmetry into colPartLds, single barrier/phase). R14: XCD-aware block swizzle —
// 512 blocks, HW round-robins blockIdx%8 across XCDs; remap so XCD k owns bands
// [k*8,(k+1)*8) with ALL their splits -> A-band reused 8x from own-XCD L2.
__global__ __launch_bounds__(256, 2)
void sim_lse_kernel(const unsigned short* __restrict__ Zb,
                    float* __restrict__ rowsumAcc,  // [MM], atomic accum
                    float* __restrict__ posArr) {   // [MM]
    __shared__ char lds[65536];                     // 2 x 32KB B buffers
    __shared__ float colPartLds[4][8][32];          // 4 KB colsum partials
    const int tid = threadIdx.x;
    const int lane = tid & 63;
    const int w = tid >> 6;
    const int wr = w >> 1, wc = w & 1;              // wave row-group / col-half
    const int r15 = lane & 15, hi = lane >> 4;
    const int bid = blockIdx.x;
    const int vid = ((bid & 7) << 6) | (bid >> 3);  // bijective XCD swizzle (512%8==0)
    const int r = vid >> 3;                         // band 0..63
    const int s = vid & 7;                          // split 0..7
    const int e0 = r & 7, e1 = e0 ^ 4;              // which splits take d=32 halves
    const int nt = 8 + ((s == e0) || (s == e1));
    const int extraHalf = (s == e1) ? 1 : 0;
    const int R0 = r * 128;

    // diag phases (s==0, t<2) never write colsums: zero own-wave slots
    if (s == 0 && lane < 32) {
        colPartLds[w][0][lane] = 0.f;
        colPartLds[w][1][lane] = 0.f;
    }

    // thread-constant swizzled k-chunk offsets (row&15 == r15 for every frag read)
    int koff[8];
    #pragma unroll
    for (int kk = 0; kk < 8; ++kk)
        koff[kk] = ((hi << 4) | (kk << 6)) ^ (r15 << 4);

    // ---- stage A band (128 rows) across both buffers, pull frags to registers ----
    stage32(Zb, lds, R0, tid);
    stage32(Zb, lds + 32768, R0 + 64, tid);
    __syncthreads();
    i32x4 qf[4][8];                                 // 64 rows x K=256 -> AGPRs
    {
        const char* ab = lds + (wr << 15);          // wr: which 64-row buffer
        #pragma unroll
        for (int mf = 0; mf < 4; ++mf)
            #pragma unroll
            for (int kk = 0; kk < 8; ++kk)
                qf[mf][kk] = *reinterpret_cast<const i32x4*>(
                    ab + (mf * 16 + r15) * 512 + koff[kk]);
    }
    __syncthreads();

    int baddr[8];                                   // wave's 32-col half of B tile
    #pragma unroll
    for (int kk = 0; kk < 8; ++kk)
        baddr[kk] = (wc * 32 + r15) * 512 + koff[kk];

    float rowsum[4][4] = {{0,0,0,0},{0,0,0,0},{0,0,0,0},{0,0,0,0}};
    const int iBase = R0 + wr * 64 + (hi << 2);     // C/D: row=(lane>>4)*4+rr

    // column start (Zb row units) of subtile step t
    auto colOf = [&](int t) -> int {
        int d = (t < 8) ? (s + ((t >> 1) << 3)) : 32;
        int half = (t < 8) ? (t & 1) : extraHalf;
        return ((r + d) & 63) * 128 + half * 64;
    };

    stage32(Zb, lds, colOf(0), tid);                // subtile 0 -> buf0

    for (int t = 0; t < nt; ++t) {
        const int C0 = colOf(t);
        const int cur = (t & 1) << 15;

        // ONE barrier per phase: implicit vmcnt(0) drains this thread's stage-t
        // loads (issued a full phase ago); barrier makes completion collective
        // AND guarantees all waves finished computing t-1, freeing its buffer.
        __syncthreads();
        if (t < nt - 1)
            stage32(Zb, lds + (cur ^ 32768), colOf(t + 1), tid);

        const int mode = (t == 8) ? 2 : ((s == 0 && t < 2) ? 1 : 0); // 0 norm,1 diag,2 pos
        #pragma unroll
        for (int nf = 0; nf < 2; ++nf) {
            f32x4 acc[4] = {{0,0,0,0},{0,0,0,0},{0,0,0,0},{0,0,0,0}};
            #pragma unroll
            for (int kk = 0; kk < 8; ++kk) {
                i32x4 b = *reinterpret_cast<const i32x4*>(lds + cur + nf * 8192 + baddr[kk]);
                #pragma unroll
                for (int mf = 0; mf < 4; ++mf)
                    asm("v_mfma_f32_16x16x32_bf16 %0, %1, %2, %0"
                        : "+v"(acc[mf]) : "a"(qf[mf][kk]), "v"(b));
            }
            const int j = C0 + wc * 32 + nf * 16 + r15;   // C/D: col=lane&15
            if (mode == 0) {
                float s8 = 0.f;
                #pragma unroll
                for (int mf = 0; mf < 4; ++mf)
                    #pragma unroll
                    for (int rr = 0; rr < 4; ++rr) {
                        float e = __builtin_amdgcn_exp2f(fmaf(acc[mf][rr], C5L2E, -C5L2E));
                        rowsum[mf][rr] += e;
                        s8 += e;
                    }
                s8 += __shfl_xor(s8, 16, 64);       // sum the 4 hi-groups (64 rows)
                s8 += __shfl_xor(s8, 32, 64);
                if (hi == 0) colPartLds[w][t][nf * 16 + r15] = s8;  // unique slot
            } else if (mode == 1) {
                #pragma unroll
                for (int mf = 0; mf < 4; ++mf)
                    #pragma unroll
                    for (int rr = 0; rr < 4; ++rr) {
                        const int i = iBase + mf * 16 + rr;
                        if (j != i)
                            rowsum[mf][rr] += __builtin_amdgcn_exp2f(fmaf(acc[mf][rr], C5L2E, -C5L2E));
                    }
            } else {
                #pragma unroll
                for (int mf = 0; mf < 4; ++mf)
                    #pragma unroll
                    for (int rr = 0; rr < 4; ++rr) {
                        const int i = iBase + mf * 16 + rr;
                        rowsum[mf][rr] += __builtin_amdgcn_exp2f(fmaf(acc[mf][rr], C5L2E, -C5L2E));
                        if (j == (i ^ 4096)) posArr[i] = acc[mf][rr] * TINV;  // unique
                    }
            }
        }
    }

    // ---- one-time colsum flush: 8 tiles x 64 cols = 512 targets = 2/thread ----
    __syncthreads();                                // colPartLds writes visible
    #pragma unroll
    for (int z = 0; z < 2; ++z) {
        const int idx = z * 256 + tid;              // t*64 + c
        const int tt = idx >> 6, c = idx & 63;
        const int ww = c >> 5;                      // which wc owns column c
        float v = colPartLds[ww][tt][c & 31] + colPartLds[2 + ww][tt][c & 31];
        if (v != 0.f) atomicAdd(&rowsumAcc[colOf(tt) + c], v);
    }

    // reduce rowsums across the 16 lanes sharing each row, flush atomically
    #pragma unroll
    for (int mf = 0; mf < 4; ++mf)
        #pragma unroll
        for (int rr = 0; rr < 4; ++rr) {
            float v = rowsum[mf][rr];
            v += __shfl_xor(v, 1, 64);
            v += __shfl_xor(v, 2, 64);
            v += __shfl_xor(v, 4, 64);
            v += __shfl_xor(v, 8, 64);
            if (r15 == 0) atomicAdd(&rowsumAcc[iBase + mf * 16 + rr], v);
        }
}

// ------- finish (single kernel): lse = log(sum)+5; out = mean(lse - pos) -------
__global__ __launch_bounds__(1024)
void fin_kernel(const float* __restrict__ rowsumAcc, const float* __restrict__ posArr,
                float* __restrict__ out) {
    const int tid = threadIdx.x;
    double v = 0.0;
    #pragma unroll
    for (int z = 0; z < 8; ++z) {
        const int i = z * 1024 + tid;
        v += (double)(logf(rowsumAcc[i]) + 5.0f - posArr[i]);
    }
    #pragma unroll
    for (int m = 1; m < 64; m <<= 1) v += __shfl_xor(v, m, 64);
    __shared__ double red[16];
    if ((tid & 63) == 0) red[tid >> 6] = v;
    __syncthreads();
    if (tid == 0) {
        double sm = 0.0;
        #pragma unroll
        for (int k = 0; k < 16; ++k) sm += red[k];
        out[0] = (float)(sm / (double)MM);
    }
}

extern "C" void kernel_launch(void* const* d_in, const int* in_sizes, int n_in,
                              void* d_out, int out_size, void* d_ws, size_t ws_size,
                              hipStream_t stream) {
    const float* Z1 = (const float*)d_in[0];
    const float* Z2 = (const float*)d_in[1];
    float* out = (float*)d_out;
    char* ws = (char*)d_ws;
    unsigned short* Zb = (unsigned short*)ws;                         // 4 MB bf16 [8192][256]
    float* posArr = (float*)(ws + 4194304);                           // 32 KB
    float* rowsumAcc = (float*)(ws + 4194304 + 32768);                // 32 KB

    nrm_kernel<<<MM / 4, 256, 0, stream>>>(Z1, Z2, Zb, rowsumAcc);
    sim_lse_kernel<<<64 * 8, 256, 0, stream>>>(Zb, rowsumAcc, posArr);
    fin_kernel<<<1, 1024, 0, stream>>>(rowsumAcc, posArr, out);
}

// Round 15
// 38.626 us; speedup vs baseline: 1.2241x; 1.0267x over previous
//
#include <hip/hip_runtime.h>
#include <cstdint>
#include <cstddef>

#define TINV 5.0f
#define C5L2E 7.2134752044448170f   // 5 * log2(e)
#define NROWS 4096
#define DDIM 256
#define MM 8192

typedef __bf16 bf16x8 __attribute__((ext_vector_type(8)));
typedef int i32x4 __attribute__((ext_vector_type(4)));
typedef float f32x4 __attribute__((ext_vector_type(4)));

typedef const void __attribute__((address_space(1)))* gas_ptr;
typedef void __attribute__((address_space(3)))* las_ptr;

// ------- normalize rows of [Z1;Z2] -> unit L2, store bf16; zero rowsumAcc -------
__global__ __launch_bounds__(256, 2)
void nrm_kernel(const float* __restrict__ Z1, const float* __restrict__ Z2,
                unsigned short* __restrict__ Zb, float* __restrict__ rowsumAcc) {
    if (blockIdx.x < 32) rowsumAcc[blockIdx.x * 256 + threadIdx.x] = 0.f;
    const int w = threadIdx.x >> 6, lane = threadIdx.x & 63;
    const int row = blockIdx.x * 4 + w;
    const float* src = row < NROWS ? Z1 + (size_t)row * DDIM
                                   : Z2 + (size_t)(row - NROWS) * DDIM;
    float4 v = reinterpret_cast<const float4*>(src)[lane];
    float ss = v.x*v.x + v.y*v.y + v.z*v.z + v.w*v.w;
    #pragma unroll
    for (int m = 1; m < 64; m <<= 1) ss += __shfl_xor(ss, m, 64);
    float inv = 1.0f / fmaxf(sqrtf(ss), 1e-12f);
    float o[4] = { v.x*inv, v.y*inv, v.z*inv, v.w*inv };
    unsigned short us[4];
    #pragma unroll
    for (int e = 0; e < 4; ++e) {           // RNE f32->bf16 (finite inputs)
        unsigned int b = __builtin_bit_cast(unsigned int, o[e]);
        b += 0x7FFFu + ((b >> 16) & 1u);
        us[e] = (unsigned short)(b >> 16);
    }
    reinterpret_cast<ushort4*>(Zb + (size_t)row * DDIM)[lane] =
        *reinterpret_cast<ushort4*>(us);
}

// ---- stage 64 rows x 512B (32KB) into LDS with 256 threads; source pre-swizzled ----
// read side uses phys_inrow = inrow ^ ((row&15)<<4)
__device__ __forceinline__ void stage32(const unsigned short* Zb, char* ldsdst,
                                        int rowStart, int tid) {
    const char* base = reinterpret_cast<const char*>(Zb) + (size_t)rowStart * 512;
    #pragma unroll
    for (int it = 0; it < 8; ++it) {
        int L = it * 4096 + tid * 16;     // linear LDS byte offset, lane-contiguous
        int row = L >> 9;                 // 0..63
        int soff = row * 512 + ((L & 511) ^ ((row & 15) << 4));
        __builtin_amdgcn_global_load_lds((gas_ptr)(base + soff), (las_ptr)(ldsdst + L),
                                         16, 0, 0);
    }
}

// -------- symmetric fused sim + exp-rowsum/colsum + pos extraction --------
// R14 schedule (64 bands x 128 rows, 8 splits, 2x2 wave grid, A in AGPR, XCD
// swizzle, single barrier/phase). R15: colsum epilogue drops the second shfl —
// per-hi-pair partials stored to colPartLds[w][t][pair][32]; cross-pair sum
// deferred to the one-time flush.
__global__ __launch_bounds__(256, 2)
void sim_lse_kernel(const unsigned short* __restrict__ Zb,
                    float* __restrict__ rowsumAcc,  // [MM], atomic accum
                    float* __restrict__ posArr) {   // [MM]
    __shared__ char lds[65536];                     // 2 x 32KB B buffers
    __shared__ float colPartLds[4][8][2][32];       // 8 KB colsum partials (per hi-pair)
    const int tid = threadIdx.x;
    const int lane = tid & 63;
    const int w = tid >> 6;
    const int wr = w >> 1, wc = w & 1;              // wave row-group / col-half
    const int r15 = lane & 15, hi = lane >> 4;
    const int bid = blockIdx.x;
    const int vid = ((bid & 7) << 6) | (bid >> 3);  // bijective XCD swizzle (512%8==0)
    const int r = vid >> 3;                         // band 0..63
    const int s = vid & 7;                          // split 0..7
    const int e0 = r & 7, e1 = e0 ^ 4;              // which splits take d=32 halves
    const int nt = 8 + ((s == e0) || (s == e1));
    const int extraHalf = (s == e1) ? 1 : 0;
    const int R0 = r * 128;

    // diag phases (s==0, t<2) never write colsums: zero own-wave slots
    if (s == 0) {
        colPartLds[w][0][lane >> 5][lane & 31] = 0.f;
        colPartLds[w][1][lane >> 5][lane & 31] = 0.f;
    }

    // thread-constant swizzled k-chunk offsets (row&15 == r15 for every frag read)
    int koff[8];
    #pragma unroll
    for (int kk = 0; kk < 8; ++kk)
        koff[kk] = ((hi << 4) | (kk << 6)) ^ (r15 << 4);

    // ---- stage A band (128 rows) across both buffers, pull frags to registers ----
    stage32(Zb, lds, R0, tid);
    stage32(Zb, lds + 32768, R0 + 64, tid);
    __syncthreads();
    i32x4 qf[4][8];                                 // 64 rows x K=256 -> AGPRs
    {
        const char* ab = lds + (wr << 15);          // wr: which 64-row buffer
        #pragma unroll
        for (int mf = 0; mf < 4; ++mf)
            #pragma unroll
            for (int kk = 0; kk < 8; ++kk)
                qf[mf][kk] = *reinterpret_cast<const i32x4*>(
                    ab + (mf * 16 + r15) * 512 + koff[kk]);
    }
    __syncthreads();

    int baddr[8];                                   // wave's 32-col half of B tile
    #pragma unroll
    for (int kk = 0; kk < 8; ++kk)
        baddr[kk] = (wc * 32 + r15) * 512 + koff[kk];

    float rowsum[4][4] = {{0,0,0,0},{0,0,0,0},{0,0,0,0},{0,0,0,0}};
    const int iBase = R0 + wr * 64 + (hi << 2);     // C/D: row=(lane>>4)*4+rr

    // column start (Zb row units) of subtile step t
    auto colOf = [&](int t) -> int {
        int d = (t < 8) ? (s + ((t >> 1) << 3)) : 32;
        int half = (t < 8) ? (t & 1) : extraHalf;
        return ((r + d) & 63) * 128 + half * 64;
    };

    stage32(Zb, lds, colOf(0), tid);                // subtile 0 -> buf0

    for (int t = 0; t < nt; ++t) {
        const int C0 = colOf(t);
        const int cur = (t & 1) << 15;

        // ONE barrier per phase (implicit vmcnt drain covers stage-t loads,
        // issued a full phase ago; also frees buffer of phase t-1).
        __syncthreads();
        if (t < nt - 1)
            stage32(Zb, lds + (cur ^ 32768), colOf(t + 1), tid);

        const int mode = (t == 8) ? 2 : ((s == 0 && t < 2) ? 1 : 0); // 0 norm,1 diag,2 pos
        #pragma unroll
        for (int nf = 0; nf < 2; ++nf) {
            f32x4 acc[4] = {{0,0,0,0},{0,0,0,0},{0,0,0,0},{0,0,0,0}};
            #pragma unroll
            for (int kk = 0; kk < 8; ++kk) {
                i32x4 b = *reinterpret_cast<const i32x4*>(lds + cur + nf * 8192 + baddr[kk]);
                #pragma unroll
                for (int mf = 0; mf < 4; ++mf)
                    asm("v_mfma_f32_16x16x32_bf16 %0, %1, %2, %0"
                        : "+v"(acc[mf]) : "a"(qf[mf][kk]), "v"(b));
            }
            const int j = C0 + wc * 32 + nf * 16 + r15;   // C/D: col=lane&15
            if (mode == 0) {
                float s8 = 0.f;
                #pragma unroll
                for (int mf = 0; mf < 4; ++mf)
                    #pragma unroll
                    for (int rr = 0; rr < 4; ++rr) {
                        float e = __builtin_amdgcn_exp2f(fmaf(acc[mf][rr], C5L2E, -C5L2E));
                        rowsum[mf][rr] += e;
                        s8 += e;
                    }
                s8 += __shfl_xor(s8, 16, 64);       // sum hi-pairs (hi^1): 32 rows
                if ((hi & 1) == 0)                  // hi=0 -> pair 0, hi=2 -> pair 1
                    colPartLds[w][t][hi >> 1][nf * 16 + r15] = s8;  // unique slot
            } else if (mode == 1) {
                #pragma unroll
                for (int mf = 0; mf < 4; ++mf)
                    #pragma unroll
                    for (int rr = 0; rr < 4; ++rr) {
                        const int i = iBase + mf * 16 + rr;
                        if (j != i)
                            rowsum[mf][rr] += __builtin_amdgcn_exp2f(fmaf(acc[mf][rr], C5L2E, -C5L2E));
                    }
            } else {
                #pragma unroll
                for (int mf = 0; mf < 4; ++mf)
                    #pragma unroll
                    for (int rr = 0; rr < 4; ++rr) {
                        const int i = iBase + mf * 16 + rr;
                        rowsum[mf][rr] += __builtin_amdgcn_exp2f(fmaf(acc[mf][rr], C5L2E, -C5L2E));
                        if (j == (i ^ 4096)) posArr[i] = acc[mf][rr] * TINV;  // unique
                    }
            }
        }
    }

    // ---- one-time colsum flush: 8 tiles x 64 cols = 512 targets = 2/thread ----
    __syncthreads();                                // colPartLds writes visible
    #pragma unroll
    for (int z = 0; z < 2; ++z) {
        const int idx = z * 256 + tid;              // t*64 + c
        const int tt = idx >> 6, c = idx & 63;
        const int ww = c >> 5;                      // which wc owns column c
        const int cc = c & 31;
        float v = colPartLds[ww][tt][0][cc] + colPartLds[ww][tt][1][cc]
                + colPartLds[2 + ww][tt][0][cc] + colPartLds[2 + ww][tt][1][cc];
        if (v != 0.f) atomicAdd(&rowsumAcc[colOf(tt) + c], v);
    }

    // reduce rowsums across the 16 lanes sharing each row, flush atomically
    #pragma unroll
    for (int mf = 0; mf < 4; ++mf)
        #pragma unroll
        for (int rr = 0; rr < 4; ++rr) {
            float v = rowsum[mf][rr];
            v += __shfl_xor(v, 1, 64);
            v += __shfl_xor(v, 2, 64);
            v += __shfl_xor(v, 4, 64);
            v += __shfl_xor(v, 8, 64);
            if (r15 == 0) atomicAdd(&rowsumAcc[iBase + mf * 16 + rr], v);
        }
}

// ------- finish (single kernel): lse = log(sum)+5; out = mean(lse - pos) -------
__global__ __launch_bounds__(1024)
void fin_kernel(const float* __restrict__ rowsumAcc, const float* __restrict__ posArr,
                float* __restrict__ out) {
    const int tid = threadIdx.x;
    double v = 0.0;
    #pragma unroll
    for (int z = 0; z < 8; ++z) {
        const int i = z * 1024 + tid;
        v += (double)(logf(rowsumAcc[i]) + 5.0f - posArr[i]);
    }
    #pragma unroll
    for (int m = 1; m < 64; m <<= 1) v += __shfl_xor(v, m, 64);
    __shared__ double red[16];
    if ((tid & 63) == 0) red[tid >> 6] = v;
    __syncthreads();
    if (tid == 0) {
        double sm = 0.0;
        #pragma unroll
        for (int k = 0; k < 16; ++k) sm += red[k];
        out[0] = (float)(sm / (double)MM);
    }
}

extern "C" void kernel_launch(void* const* d_in, const int* in_sizes, int n_in,
                              void* d_out, int out_size, void* d_ws, size_t ws_size,
                              hipStream_t stream) {
    const float* Z1 = (const float*)d_in[0];
    const float* Z2 = (const float*)d_in[1];
    float* out = (float*)d_out;
    char* ws = (char*)d_ws;
    unsigned short* Zb = (unsigned short*)ws;                         // 4 MB bf16 [8192][256]
    float* posArr = (float*)(ws + 4194304);                           // 32 KB
    float* rowsumAcc = (float*)(ws + 4194304 + 32768);                // 32 KB

    nrm_kernel<<<MM / 4, 256, 0, stream>>>(Z1, Z2, Zb, rowsumAcc);
    sim_lse_kernel<<<64 * 8, 256, 0, stream>>>(Zb, rowsumAcc, posArr);
    fin_kernel<<<1, 1024, 0, stream>>>(rowsumAcc, posArr, out);
}